// Round 11
// baseline (6480.677 us; speedup 1.0000x reference)
//
#include <hip/hip_runtime.h>

// ODE_Vanilla scan: B=128, T=256, I=256, H=1024, C=10, fp32 throughout.
//   phase1: v = a*h - relu(h@Wh + XW[t])   (XW = X@Wx + b precomputed)
//   phase2: u = v@Wh^T; grad = a*v - (phi>0)*u; h -= LR*grad; out[b,t,:]=h@fc_w+fc_b
// R13 = R12 (champion 5.95 ms) + ONE structural delta: 16-row blocks that
// share W via LDS. 512 blocks x 512 threads (8 waves = two 8-row halves,
// each half = R12's exact proven layout: c4 x kk, acc[8], value-split
// reduce). W k-chunk (16 KB) staged cooperatively once per chunk (2 f4 per
// thread, register-dbuf so next chunk's loads overlap compute); XOR-swizzled
// LDS (cq ^ (krow&3)) hits the 8-cy ds_read_b128 bank floor. W traffic per
// dispatch halves: 64 -> 32 MB.
// Hard constraints (measured): acc <= 8 float4 (R6/R9); grid <= co-resident
// (R8); no agent-scope in-kernel barriers (R5); plain cached loads (R10);
// LDS-form FC tail (R10/R11); one variable per round.

constexpr int Bsz = 128, Tn = 256, In = 256, Hn = 1024, Cn = 10;
constexpr float LR = 0.001f;

__global__ __launch_bounds__(256) void k_transpose(const float* __restrict__ W,
                                                   float* __restrict__ WT) {
  __shared__ float tile[32][33];
  const int bx = blockIdx.x * 32, by = blockIdx.y * 32;
  const int tx = threadIdx.x & 31, ty = threadIdx.x >> 5;
#pragma unroll
  for (int dy = 0; dy < 32; dy += 8)
    tile[ty + dy][tx] = W[(size_t)(by + ty + dy) * Hn + bx + tx];
  __syncthreads();
#pragma unroll
  for (int dy = 0; dy < 32; dy += 8)
    WT[(size_t)(bx + ty + dy) * Hn + by + tx] = tile[tx][ty + dy];
}

__global__ __launch_bounds__(256) void k_init(float* __restrict__ out,
                                              const float* __restrict__ fc_b,
                                              float* __restrict__ h_cur,
                                              const float* __restrict__ hidden) {
  const int i = blockIdx.x * blockDim.x + threadIdx.x;
  if (i < Bsz * Tn * Cn) out[i] = fc_b[i % Cn];
  if (i < Bsz * Hn) h_cur[i] = hidden[i];
}

__device__ __forceinline__ void fma4(float4& a, float s, const float4& w) {
  a.x = fmaf(s, w.x, a.x);
  a.y = fmaf(s, w.y, a.y);
  a.z = fmaf(s, w.z, a.z);
  a.w = fmaf(s, w.w, a.w);
}

__device__ __forceinline__ float4 shfl4(float4 v, int m) {
  v.x = __shfl_xor(v.x, m, 64);
  v.y = __shfl_xor(v.y, m, 64);
  v.z = __shfl_xor(v.z, m, 64);
  v.w = __shfl_xor(v.w, m, 64);
  return v;
}

__device__ __forceinline__ float4 add4(float4 a, float4 b) {
  return make_float4(a.x + b.x, a.y + b.y, a.z + b.z, a.w + b.w);
}

// XW[t][b][n] = sum_k X[b][t][k]*Wx[k][n] + bias[n].
__global__ __launch_bounds__(256) void k_xw(const float* __restrict__ X,
                                            const float* __restrict__ Wx,
                                            const float* __restrict__ bias,
                                            float* __restrict__ xw) {
  const int nt = blockIdx.x & 15, mt = blockIdx.x >> 4;
  const int t = mt >> 1, b0 = (mt & 1) * 64;
  const int cl = threadIdx.x & 15, rg = threadIdx.x >> 4;
  const int col = nt * 64 + cl * 4;
  const int row = b0 + rg * 4;
  float4 acc0 = {0, 0, 0, 0}, acc1 = {0, 0, 0, 0}, acc2 = {0, 0, 0, 0},
         acc3 = {0, 0, 0, 0};
  const size_t xstride = (size_t)Tn * In;
  const float* xp = X + ((size_t)row * Tn + t) * In;
  const float* wp = Wx + col;
#pragma unroll 2
  for (int k = 0; k < In; k += 4) {
    const float4 x0 = *(const float4*)(xp + k);
    const float4 x1 = *(const float4*)(xp + xstride + k);
    const float4 x2 = *(const float4*)(xp + 2 * xstride + k);
    const float4 x3 = *(const float4*)(xp + 3 * xstride + k);
    const float4 w0 = *(const float4*)(wp + (size_t)k * Hn);
    const float4 w1 = *(const float4*)(wp + (size_t)(k + 1) * Hn);
    const float4 w2 = *(const float4*)(wp + (size_t)(k + 2) * Hn);
    const float4 w3 = *(const float4*)(wp + (size_t)(k + 3) * Hn);
    fma4(acc0, x0.x, w0); fma4(acc0, x0.y, w1); fma4(acc0, x0.z, w2); fma4(acc0, x0.w, w3);
    fma4(acc1, x1.x, w0); fma4(acc1, x1.y, w1); fma4(acc1, x1.z, w2); fma4(acc1, x1.w, w3);
    fma4(acc2, x2.x, w0); fma4(acc2, x2.y, w1); fma4(acc2, x2.z, w2); fma4(acc2, x2.w, w3);
    fma4(acc3, x3.x, w0); fma4(acc3, x3.y, w1); fma4(acc3, x3.z, w2); fma4(acc3, x3.w, w3);
  }
  const float4 b4 = *(const float4*)(bias + col);
  float4 o[4] = {acc0, acc1, acc2, acc3};
#pragma unroll
  for (int i = 0; i < 4; i++) {
    float4 v = o[i];
    v.x += b4.x; v.y += b4.y; v.z += b4.z; v.w += b4.w;
    *(float4*)(xw + ((size_t)t * Bsz + row + i) * Hn + col) = v;
  }
}

// LDS slab: chunk of W, 256 krows x 4 col-quads, XOR-swizzled float4 index.
#define WSLOT(krow, cq) (((krow) << 2) + ((cq) ^ ((krow)&3)))

// Value-splitting reduce over ks lane bits 2..5 (validated R5/R7/R12).
__device__ __forceinline__ void reduce_vs(float4 acc[8], int c4, int ksw,
                                          int wv, float (*part)[8][16]) {
  const bool u1 = ksw & 1;
#pragma unroll
  for (int i = 0; i < 4; i++) {
    const float4 snd = u1 ? acc[i] : acc[i + 4];
    const float4 kp = u1 ? acc[i + 4] : acc[i];
    acc[i] = add4(kp, shfl4(snd, 4));
  }
  const bool u2 = ksw & 2;
#pragma unroll
  for (int i = 0; i < 2; i++) {
    const float4 snd = u2 ? acc[i] : acc[i + 2];
    const float4 kp = u2 ? acc[i + 2] : acc[i];
    acc[i] = add4(kp, shfl4(snd, 8));
  }
  const bool u3 = ksw & 4;
  {
    const float4 snd = u3 ? acc[0] : acc[1];
    const float4 kp = u3 ? acc[1] : acc[0];
    acc[0] = add4(kp, shfl4(snd, 16));
  }
  const bool u4 = ksw & 8;
  float sx = u4 ? acc[0].x : acc[0].z;
  float sy = u4 ? acc[0].y : acc[0].w;
  const float kx = u4 ? acc[0].z : acc[0].x;
  const float ky = u4 ? acc[0].w : acc[0].y;
  sx = __shfl_xor(sx, 32, 64);
  sy = __shfl_xor(sy, 32, 64);
  const int r_own = ((ksw & 1) << 2) | (ksw & 2) | ((ksw >> 2) & 1);
  const int c_own = 4 * c4 + (u4 ? 2 : 0);
  *(float2*)&part[wv][r_own][c_own] = make_float2(kx + sx, ky + sy);
}

// Shared GEMM core: 16 rows x 16 cols, W via LDS (staged, reg-dbuf), rows
// (h or v) direct from global. Thread tid: half g = tid>>8 owns rows
// 8g..8g+7; within half: c4 = tid&3, kk = (tid>>2)&63 (R12 layout).
// Result: part[2][4][8][16] partials, combined by caller's epilogue.
__device__ __forceinline__ void gemm16_lds(const float* __restrict__ rows,
                                           const float* __restrict__ W,
                                           int c0, int tid, float4* wslab,
                                           float4 acc[8]) {
  const int g = tid >> 8;
  const int c4 = tid & 3, kk = (tid >> 2) & 63;
  const float* rbase = rows + (size_t)(g * 8) * Hn;
  // stage-load element for this thread: f in {tid, tid+512} of the 1024-f4
  // slab; krow = f>>2, cq = f&3, global col = c0 + 4*cq.
  const int f0 = tid, f1 = tid + 512;
  const int kr0 = f0 >> 2, cq0 = f0 & 3, kr1 = f1 >> 2, cq1 = f1 & 3;
  const float* g0 = W + (size_t)kr0 * Hn + c0 + 4 * cq0;
  const float* g1 = W + (size_t)kr1 * Hn + c0 + 4 * cq1;
  const int s0i = WSLOT(kr0, cq0), s1i = WSLOT(kr1, cq1);

  float4 s0 = *(const float4*)(g0);
  float4 s1 = *(const float4*)(g1);
#pragma unroll
  for (int q = 0; q < 4; q++) {
    __syncthreads();  // prior chunk's reads done before overwrite
    wslab[s0i] = s0;
    wslab[s1i] = s1;
    if (q < 3) {  // issue next chunk's loads; latency overlaps sync+compute
      s0 = *(const float4*)(g0 + (size_t)256 * (q + 1) * Hn);
      s1 = *(const float4*)(g1 + (size_t)256 * (q + 1) * Hn);
    }
    __syncthreads();  // slab visible
    const int klocal = 4 * kk;
    const float4 w0 = wslab[WSLOT(klocal, c4)];
    const float4 w1 = wslab[WSLOT(klocal + 1, c4)];
    const float4 w2 = wslab[WSLOT(klocal + 2, c4)];
    const float4 w3 = wslab[WSLOT(klocal + 3, c4)];
    const int k = klocal + 256 * q;
#pragma unroll
    for (int r = 0; r < 8; r++) {
      const float4 h4 = *(const float4*)(rbase + (size_t)r * Hn + k);
      fma4(acc[r], h4.x, w0);
      fma4(acc[r], h4.y, w1);
      fma4(acc[r], h4.z, w2);
      fma4(acc[r], h4.w, w3);
    }
  }
}

// grid 512 = rt(8, 16 rows) x ct(64, 16 cols); block 512 = 2 halves x 256.
template <int PRE>
__global__ __launch_bounds__(512, 4) void k_phase1(
    const float* __restrict__ h, const float* __restrict__ X,
    const float* __restrict__ Wh, const float* __restrict__ Wx,
    const float* __restrict__ bias, const float* __restrict__ alpha,
    const float* __restrict__ xw, float* __restrict__ v_out, int t) {
  __shared__ float4 wslab[1024];        // 16 KB staged W chunk
  __shared__ float part[2][4][8][16];   // 16 KB cross-wave partials
  const int ct = blockIdx.x & 63, rt = blockIdx.x >> 6;
  const int c0 = ct * 16, r0 = rt * 16;
  const int tid = threadIdx.x;
  const int g = tid >> 8, c4 = tid & 3, kk = (tid >> 2) & 63;
  const int wvh = (tid >> 6) & 3, ksw = (tid & 63) >> 2;
  const float* hbase = h + (size_t)r0 * Hn;
  const float av = alpha[0];

  // epilogue prefetch (R12-proven): r = tid>>4 in 0..15, c = tid&15
  float a1 = 0.f, hv = 0.f;
  if (tid < 256) {
    const int r = tid >> 4, c = tid & 15;
    a1 = PRE ? xw[((size_t)t * Bsz + r0 + r) * Hn + c0 + c] : bias[c0 + c];
    hv = hbase[(size_t)r * Hn + c0 + c];
  }

  float4 acc[8];
#pragma unroll
  for (int r = 0; r < 8; r++) acc[r] = {0.f, 0.f, 0.f, 0.f};
  gemm16_lds(hbase, Wh + c0, c0 - c0, tid, wslab, acc);  // W col base folded
  if (!PRE) {  // x@Wx inline per half: thread kk owns Wx row-quad 4kk
    const int kx = 4 * kk;
    const float* Wp = Wx + (size_t)kx * Hn + c0 + 4 * c4;
    const float4 w0 = *(const float4*)(Wp);
    const float4 w1 = *(const float4*)(Wp + Hn);
    const float4 w2 = *(const float4*)(Wp + 2 * Hn);
    const float4 w3 = *(const float4*)(Wp + 3 * Hn);
    const float* rbase = hbase;  // row indexing below uses absolute rows
#pragma unroll
    for (int r = 0; r < 8; r++) {
      const float4 x4 =
          *(const float4*)(X + ((size_t)(r0 + 8 * g + r) * Tn + t) * In + kx);
      fma4(acc[r], x4.x, w0);
      fma4(acc[r], x4.y, w1);
      fma4(acc[r], x4.z, w2);
      fma4(acc[r], x4.w, w3);
    }
    (void)rbase;
  }
  reduce_vs(acc, c4, ksw, wvh, part[g]);
  __syncthreads();
  if (tid < 256) {
    const int r = tid >> 4, c = tid & 15;
    const int g2 = r >> 3, rl = r & 7;
    const float u = part[g2][0][rl][c] + part[g2][1][rl][c] +
                    part[g2][2][rl][c] + part[g2][3][rl][c];
    v_out[(size_t)(r0 + r) * Hn + c0 + c] = av * hv - fmaxf(u + a1, 0.f);
  }
}

__global__ __launch_bounds__(512, 4) void k_phase2(
    float* __restrict__ h, const float* __restrict__ v_in,
    const float* __restrict__ WT, const float* __restrict__ alpha,
    const float* __restrict__ fc_w, float* __restrict__ out,
    float* __restrict__ hfin, int t, int last) {
  __shared__ float4 wslab[1024];
  __shared__ float part[2][4][8][16];
  __shared__ float hn_s[16][16];
  const int ct = blockIdx.x & 63, rt = blockIdx.x >> 6;
  const int c0 = ct * 16, r0 = rt * 16;
  const int tid = threadIdx.x;
  const int g = tid >> 8, c4 = tid & 3, kk = (tid >> 2) & 63;
  const int wvh = (tid >> 6) & 3, ksw = (tid & 63) >> 2;
  const float* vbase = v_in + (size_t)r0 * Hn;
  const float av = alpha[0];
  (void)g; (void)kk; (void)c4;

  float hv = 0.f, vv = 0.f;
  if (tid < 256) {
    const int r = tid >> 4, c = tid & 15;
    hv = h[(size_t)(r0 + r) * Hn + c0 + c];
    vv = vbase[(size_t)r * Hn + c0 + c];
  }

  float4 acc[8];
#pragma unroll
  for (int r = 0; r < 8; r++) acc[r] = {0.f, 0.f, 0.f, 0.f};
  gemm16_lds(vbase, WT + c0, 0, tid, wslab, acc);
  reduce_vs(acc, tid & 3, ksw, wvh, part[tid >> 8]);
  __syncthreads();
  if (tid < 256) {
    const int r = tid >> 4, c = tid & 15;
    const int g2 = r >> 3, rl = r & 7;
    const float u = part[g2][0][rl][c] + part[g2][1][rl][c] +
                    part[g2][2][rl][c] + part[g2][3][rl][c];
    const size_t hoff = (size_t)(r0 + r) * Hn + c0 + c;
    // phi = a*h - v; grad = a*v - (phi>0)*u; hn = h - LR*grad
    const float hn = hv - LR * (av * vv - ((av * hv - vv) > 0.f ? u : 0.f));
    h[hoff] = hn;
    if (last) hfin[hoff] = hn;
    hn_s[r][c] = hn;
  }
  __syncthreads();
  if (tid < 160) {  // FC partial over this block's 16 cols, 16 rows
    const int rr = tid / 10, c = tid % 10;
    float s = 0.f;
#pragma unroll
    for (int jj = 0; jj < 16; jj++)
      s += hn_s[rr][jj] * fc_w[(size_t)(c0 + jj) * Cn + c];
    atomicAdd(&out[((size_t)(r0 + rr) * Tn + t) * Cn + c], s);
  }
}

extern "C" void kernel_launch(void* const* d_in, const int* in_sizes, int n_in,
                              void* d_out, int out_size, void* d_ws, size_t ws_size,
                              hipStream_t stream) {
  const float* X      = (const float*)d_in[0];
  const float* hidden = (const float*)d_in[1];
  const float* alpha  = (const float*)d_in[2];
  const float* bias   = (const float*)d_in[3];
  const float* Wh     = (const float*)d_in[4];
  const float* Wx     = (const float*)d_in[5];
  const float* fc_w   = (const float*)d_in[6];
  const float* fc_b   = (const float*)d_in[7];
  float* out  = (float*)d_out;
  float* hfin = out + (size_t)Bsz * Tn * Cn;

  char* ws = (char*)d_ws;
  float* WhT   = (float*)ws;                        // 4 MB
  float* h_cur = WhT + (size_t)Hn * Hn;
  float* v_buf = h_cur + (size_t)Bsz * Hn;
  float* XW    = v_buf + (size_t)Bsz * Hn;          // 134 MB, [t][b][n]
  const size_t need =
      ((size_t)Hn * Hn + 2 * (size_t)Bsz * Hn + (size_t)Bsz * Tn * Hn) *
      sizeof(float);
  const bool pre = ws_size >= need;

  k_transpose<<<dim3(32, 32), 256, 0, stream>>>(Wh, WhT);
  k_init<<<(Bsz * Tn * Cn + 255) / 256, 256, 0, stream>>>(out, fc_b, h_cur,
                                                          hidden);
  if (pre) k_xw<<<8192, 256, 0, stream>>>(X, Wx, bias, XW);
  for (int t = 0; t < Tn; t++) {
    if (pre)
      k_phase1<1><<<512, 512, 0, stream>>>(h_cur, X, Wh, Wx, bias, alpha, XW,
                                           v_buf, t);
    else
      k_phase1<0><<<512, 512, 0, stream>>>(h_cur, X, Wh, Wx, bias, alpha, XW,
                                           v_buf, t);
    k_phase2<<<512, 512, 0, stream>>>(h_cur, v_buf, WhT, alpha, fc_w, out,
                                      hfin, t, t == Tn - 1);
  }
}

// Round 12
// 5857.380 us; speedup vs baseline: 1.1064x; 1.1064x over previous
//
#include <hip/hip_runtime.h>

// ODE_Vanilla scan: B=128, T=256, I=256, H=1024, C=10, fp32 throughout.
//   phase1: v = a*h - relu(h@Wh + XW[t])   (XW = X@Wx + b precomputed)
//   phase2: u = v@Wh^T; grad = a*v - (phi>0)*u; h -= LR*grad; out[b,t,:]=h@fc_w+fc_b
// R14 = R12 (champion 5.95 ms) + ONE delta: 512 blocks x 512 threads, two
// independent 8-row HALVES per block, each half byte-exact R12 (gemm8g from
// global, acc[8], value-split reduce). Both halves issue identical W address
// streams on the same CU -> second stream hits L1 (32 KB/CU). W-redundancy
// halves with ZERO staging cost (R13's LDS version paid +1.9us in sync+DS).
// Hard constraints (measured): acc <= 8 float4 (R6/R9); grid <= co-resident
// (R8); no agent-scope in-kernel barriers (R5); plain cached loads (R10);
// LDS-form FC tail (R10/R11); one variable per round.

constexpr int Bsz = 128, Tn = 256, In = 256, Hn = 1024, Cn = 10;
constexpr float LR = 0.001f;

__global__ __launch_bounds__(256) void k_transpose(const float* __restrict__ W,
                                                   float* __restrict__ WT) {
  __shared__ float tile[32][33];
  const int bx = blockIdx.x * 32, by = blockIdx.y * 32;
  const int tx = threadIdx.x & 31, ty = threadIdx.x >> 5;
#pragma unroll
  for (int dy = 0; dy < 32; dy += 8)
    tile[ty + dy][tx] = W[(size_t)(by + ty + dy) * Hn + bx + tx];
  __syncthreads();
#pragma unroll
  for (int dy = 0; dy < 32; dy += 8)
    WT[(size_t)(bx + ty + dy) * Hn + by + tx] = tile[tx][ty + dy];
}

__global__ __launch_bounds__(256) void k_init(float* __restrict__ out,
                                              const float* __restrict__ fc_b,
                                              float* __restrict__ h_cur,
                                              const float* __restrict__ hidden) {
  const int i = blockIdx.x * blockDim.x + threadIdx.x;
  if (i < Bsz * Tn * Cn) out[i] = fc_b[i % Cn];
  if (i < Bsz * Hn) h_cur[i] = hidden[i];
}

__device__ __forceinline__ void fma4(float4& a, float s, const float4& w) {
  a.x = fmaf(s, w.x, a.x);
  a.y = fmaf(s, w.y, a.y);
  a.z = fmaf(s, w.z, a.z);
  a.w = fmaf(s, w.w, a.w);
}

__device__ __forceinline__ float4 shfl4(float4 v, int m) {
  v.x = __shfl_xor(v.x, m, 64);
  v.y = __shfl_xor(v.y, m, 64);
  v.z = __shfl_xor(v.z, m, 64);
  v.w = __shfl_xor(v.w, m, 64);
  return v;
}

__device__ __forceinline__ float4 add4(float4 a, float4 b) {
  return make_float4(a.x + b.x, a.y + b.y, a.z + b.z, a.w + b.w);
}

// XW[t][b][n] = sum_k X[b][t][k]*Wx[k][n] + bias[n].
__global__ __launch_bounds__(256) void k_xw(const float* __restrict__ X,
                                            const float* __restrict__ Wx,
                                            const float* __restrict__ bias,
                                            float* __restrict__ xw) {
  const int nt = blockIdx.x & 15, mt = blockIdx.x >> 4;
  const int t = mt >> 1, b0 = (mt & 1) * 64;
  const int cl = threadIdx.x & 15, rg = threadIdx.x >> 4;
  const int col = nt * 64 + cl * 4;
  const int row = b0 + rg * 4;
  float4 acc0 = {0, 0, 0, 0}, acc1 = {0, 0, 0, 0}, acc2 = {0, 0, 0, 0},
         acc3 = {0, 0, 0, 0};
  const size_t xstride = (size_t)Tn * In;
  const float* xp = X + ((size_t)row * Tn + t) * In;
  const float* wp = Wx + col;
#pragma unroll 2
  for (int k = 0; k < In; k += 4) {
    const float4 x0 = *(const float4*)(xp + k);
    const float4 x1 = *(const float4*)(xp + xstride + k);
    const float4 x2 = *(const float4*)(xp + 2 * xstride + k);
    const float4 x3 = *(const float4*)(xp + 3 * xstride + k);
    const float4 w0 = *(const float4*)(wp + (size_t)k * Hn);
    const float4 w1 = *(const float4*)(wp + (size_t)(k + 1) * Hn);
    const float4 w2 = *(const float4*)(wp + (size_t)(k + 2) * Hn);
    const float4 w3 = *(const float4*)(wp + (size_t)(k + 3) * Hn);
    fma4(acc0, x0.x, w0); fma4(acc0, x0.y, w1); fma4(acc0, x0.z, w2); fma4(acc0, x0.w, w3);
    fma4(acc1, x1.x, w0); fma4(acc1, x1.y, w1); fma4(acc1, x1.z, w2); fma4(acc1, x1.w, w3);
    fma4(acc2, x2.x, w0); fma4(acc2, x2.y, w1); fma4(acc2, x2.z, w2); fma4(acc2, x2.w, w3);
    fma4(acc3, x3.x, w0); fma4(acc3, x3.y, w1); fma4(acc3, x3.z, w2); fma4(acc3, x3.w, w3);
  }
  const float4 b4 = *(const float4*)(bias + col);
  float4 o[4] = {acc0, acc1, acc2, acc3};
#pragma unroll
  for (int i = 0; i < 4; i++) {
    float4 v = o[i];
    v.x += b4.x; v.y += b4.y; v.z += b4.z; v.w += b4.w;
    *(float4*)(xw + ((size_t)t * Bsz + row + i) * Hn + col) = v;
  }
}

// 8-rows x 16-cols x K=1024 panel GEMM; per-half thread = c4(4) x kk(64).
// Rows read straight from global; W from global (both halves of the block
// issue identical W streams -> second hits L1). Byte-exact R12 core.
__device__ __forceinline__ void gemm8g(const float* __restrict__ rows,
                                       const float* __restrict__ W, int kk,
                                       int col, float4 acc[8]) {
#pragma unroll
  for (int q = 0; q < 4; q++) {
    const int k = 4 * kk + 256 * q;
    const float* Wp = W + (size_t)k * Hn + col;
    const float4 w0 = *(const float4*)(Wp);
    const float4 w1 = *(const float4*)(Wp + Hn);
    const float4 w2 = *(const float4*)(Wp + 2 * Hn);
    const float4 w3 = *(const float4*)(Wp + 3 * Hn);
#pragma unroll
    for (int r = 0; r < 8; r++) {
      const float4 h4 = *(const float4*)(rows + (size_t)r * Hn + k);
      fma4(acc[r], h4.x, w0);
      fma4(acc[r], h4.y, w1);
      fma4(acc[r], h4.z, w2);
      fma4(acc[r], h4.w, w3);
    }
  }
}

// Value-splitting reduce over ks lane bits 2..5 (validated R5/R7/R12).
__device__ __forceinline__ void reduce_vs(float4 acc[8], int c4, int ksw,
                                          int wv, float (*part)[8][16]) {
  const bool u1 = ksw & 1;
#pragma unroll
  for (int i = 0; i < 4; i++) {
    const float4 snd = u1 ? acc[i] : acc[i + 4];
    const float4 kp = u1 ? acc[i + 4] : acc[i];
    acc[i] = add4(kp, shfl4(snd, 4));
  }
  const bool u2 = ksw & 2;
#pragma unroll
  for (int i = 0; i < 2; i++) {
    const float4 snd = u2 ? acc[i] : acc[i + 2];
    const float4 kp = u2 ? acc[i + 2] : acc[i];
    acc[i] = add4(kp, shfl4(snd, 8));
  }
  const bool u3 = ksw & 4;
  {
    const float4 snd = u3 ? acc[0] : acc[1];
    const float4 kp = u3 ? acc[1] : acc[0];
    acc[0] = add4(kp, shfl4(snd, 16));
  }
  const bool u4 = ksw & 8;
  float sx = u4 ? acc[0].x : acc[0].z;
  float sy = u4 ? acc[0].y : acc[0].w;
  const float kx = u4 ? acc[0].z : acc[0].x;
  const float ky = u4 ? acc[0].w : acc[0].y;
  sx = __shfl_xor(sx, 32, 64);
  sy = __shfl_xor(sy, 32, 64);
  const int r_own = ((ksw & 1) << 2) | (ksw & 2) | ((ksw >> 2) & 1);
  const int c_own = 4 * c4 + (u4 ? 2 : 0);
  *(float2*)&part[wv][r_own][c_own] = make_float2(kx + sx, ky + sy);
}

// grid 512 = rt(8, 16 rows) x ct(64, 16 cols); block 512 = half g(2) x 256.
// Half g owns rows r0+8g..r0+8g+7 and is byte-exact R12 internally.
template <int PRE>
__global__ __launch_bounds__(512, 4) void k_phase1(
    const float* __restrict__ h, const float* __restrict__ X,
    const float* __restrict__ Wh, const float* __restrict__ Wx,
    const float* __restrict__ bias, const float* __restrict__ alpha,
    const float* __restrict__ xw, float* __restrict__ v_out, int t) {
  __shared__ float part[2][4][8][16];
  const int ct = blockIdx.x & 63, rt = blockIdx.x >> 6;
  const int c0 = ct * 16, r0 = rt * 16;
  const int tid = threadIdx.x;
  const int g = tid >> 8;
  const int c4 = tid & 3, kk = (tid >> 2) & 63;
  const int col = c0 + 4 * c4;
  const int wvh = (tid >> 6) & 3, ksw = (tid & 63) >> 2;
  const float* hbase = h + (size_t)r0 * Hn;      // 16-row tile base
  const float* hhalf = hbase + (size_t)(8 * g) * Hn;  // this half's 8 rows
  const float av = alpha[0];

  // epilogue prefetch (R12-proven), now 16 rows via tid<256
  float a1 = 0.f, hv = 0.f;
  if (tid < 256) {
    const int r = tid >> 4, c = tid & 15;
    a1 = PRE ? xw[((size_t)t * Bsz + r0 + r) * Hn + c0 + c] : bias[c0 + c];
    hv = hbase[(size_t)r * Hn + c0 + c];
  }

  float4 acc[8];
#pragma unroll
  for (int r = 0; r < 8; r++) acc[r] = {0.f, 0.f, 0.f, 0.f};
  gemm8g(hhalf, Wh, kk, col, acc);
  if (!PRE) {  // x@Wx inline per half: thread kk owns Wx row-quad 4kk
    const int kx = 4 * kk;
    const float* Wp = Wx + (size_t)kx * Hn + col;
    const float4 w0 = *(const float4*)(Wp);
    const float4 w1 = *(const float4*)(Wp + Hn);
    const float4 w2 = *(const float4*)(Wp + 2 * Hn);
    const float4 w3 = *(const float4*)(Wp + 3 * Hn);
#pragma unroll
    for (int r = 0; r < 8; r++) {
      const float4 x4 = *(const float4*)(
          X + ((size_t)(r0 + 8 * g + r) * Tn + t) * In + kx);
      fma4(acc[r], x4.x, w0);
      fma4(acc[r], x4.y, w1);
      fma4(acc[r], x4.z, w2);
      fma4(acc[r], x4.w, w3);
    }
  }
  reduce_vs(acc, c4, ksw, wvh, part[g]);
  __syncthreads();
  if (tid < 256) {
    const int r = tid >> 4, c = tid & 15;
    const int g2 = r >> 3, rl = r & 7;
    const float u = part[g2][0][rl][c] + part[g2][1][rl][c] +
                    part[g2][2][rl][c] + part[g2][3][rl][c];
    v_out[(size_t)(r0 + r) * Hn + c0 + c] = av * hv - fmaxf(u + a1, 0.f);
  }
}

__global__ __launch_bounds__(512, 4) void k_phase2(
    float* __restrict__ h, const float* __restrict__ v_in,
    const float* __restrict__ WT, const float* __restrict__ alpha,
    const float* __restrict__ fc_w, float* __restrict__ out,
    float* __restrict__ hfin, int t, int last) {
  __shared__ float part[2][4][8][16];
  __shared__ float hn_s[16][16];
  const int ct = blockIdx.x & 63, rt = blockIdx.x >> 6;
  const int c0 = ct * 16, r0 = rt * 16;
  const int tid = threadIdx.x;
  const int g = tid >> 8;
  const int c4 = tid & 3, kk = (tid >> 2) & 63;
  const int col = c0 + 4 * c4;
  const int wvh = (tid >> 6) & 3, ksw = (tid & 63) >> 2;
  const float* vbase = v_in + (size_t)r0 * Hn;
  const float* vhalf = vbase + (size_t)(8 * g) * Hn;
  const float av = alpha[0];

  float hv = 0.f, vv = 0.f;
  if (tid < 256) {
    const int r = tid >> 4, c = tid & 15;
    hv = h[(size_t)(r0 + r) * Hn + c0 + c];
    vv = vbase[(size_t)r * Hn + c0 + c];
  }

  float4 acc[8];
#pragma unroll
  for (int r = 0; r < 8; r++) acc[r] = {0.f, 0.f, 0.f, 0.f};
  gemm8g(vhalf, WT, kk, col, acc);
  reduce_vs(acc, c4, ksw, wvh, part[g]);
  __syncthreads();
  if (tid < 256) {
    const int r = tid >> 4, c = tid & 15;
    const int g2 = r >> 3, rl = r & 7;
    const float u = part[g2][0][rl][c] + part[g2][1][rl][c] +
                    part[g2][2][rl][c] + part[g2][3][rl][c];
    const size_t hoff = (size_t)(r0 + r) * Hn + c0 + c;
    // phi = a*h - v; grad = a*v - (phi>0)*u; hn = h - LR*grad
    const float hn = hv - LR * (av * vv - ((av * hv - vv) > 0.f ? u : 0.f));
    h[hoff] = hn;
    if (last) hfin[hoff] = hn;
    hn_s[r][c] = hn;
  }
  __syncthreads();
  if (tid < 160) {  // FC partial over this block's 16 cols, 16 rows (R7 form)
    const int rr = tid / 10, c = tid % 10;
    float s = 0.f;
#pragma unroll
    for (int jj = 0; jj < 16; jj++)
      s += hn_s[rr][jj] * fc_w[(size_t)(c0 + jj) * Cn + c];
    atomicAdd(&out[((size_t)(r0 + rr) * Tn + t) * Cn + c], s);
  }
}

extern "C" void kernel_launch(void* const* d_in, const int* in_sizes, int n_in,
                              void* d_out, int out_size, void* d_ws, size_t ws_size,
                              hipStream_t stream) {
  const float* X      = (const float*)d_in[0];
  const float* hidden = (const float*)d_in[1];
  const float* alpha  = (const float*)d_in[2];
  const float* bias   = (const float*)d_in[3];
  const float* Wh     = (const float*)d_in[4];
  const float* Wx     = (const float*)d_in[5];
  const float* fc_w   = (const float*)d_in[6];
  const float* fc_b   = (const float*)d_in[7];
  float* out  = (float*)d_out;
  float* hfin = out + (size_t)Bsz * Tn * Cn;

  char* ws = (char*)d_ws;
  float* WhT   = (float*)ws;                        // 4 MB
  float* h_cur = WhT + (size_t)Hn * Hn;
  float* v_buf = h_cur + (size_t)Bsz * Hn;
  float* XW    = v_buf + (size_t)Bsz * Hn;          // 134 MB, [t][b][n]
  const size_t need =
      ((size_t)Hn * Hn + 2 * (size_t)Bsz * Hn + (size_t)Bsz * Tn * Hn) *
      sizeof(float);
  const bool pre = ws_size >= need;

  k_transpose<<<dim3(32, 32), 256, 0, stream>>>(Wh, WhT);
  k_init<<<(Bsz * Tn * Cn + 255) / 256, 256, 0, stream>>>(out, fc_b, h_cur,
                                                          hidden);
  if (pre) k_xw<<<8192, 256, 0, stream>>>(X, Wx, bias, XW);
  for (int t = 0; t < Tn; t++) {
    if (pre)
      k_phase1<1><<<512, 512, 0, stream>>>(h_cur, X, Wh, Wx, bias, alpha, XW,
                                           v_buf, t);
    else
      k_phase1<0><<<512, 512, 0, stream>>>(h_cur, X, Wh, Wx, bias, alpha, XW,
                                           v_buf, t);
    k_phase2<<<512, 512, 0, stream>>>(h_cur, v_buf, WhT, alpha, fc_w, out,
                                      hfin, t, t == Tn - 1);
  }
}

// Round 13
// 5771.393 us; speedup vs baseline: 1.1229x; 1.0149x over previous
//
#include <hip/hip_runtime.h>

// ODE_Vanilla scan: B=128, T=256, I=256, H=1024, C=10, fp32 throughout.
//   phase1: v = a*h - relu(h@Wh + XW[t])   (XW = X@Wx + b precomputed)
//   phase2: u = v@Wh^T; grad = a*v - (phi>0)*u; h -= LR*grad; out[b,t,:]=h@fc_w+fc_b
// R15 = R14 (champion 5.86 ms) + ONE delta: W packed col-tile-major at setup
// (W_p[ct][k][16], 16 KB per col-tile). R14's W loads strode 4 KB (Hn*4) ->
// all lines hit a few L1 sets -> self-eviction defeated the two-half L1
// sharing. Packed: each wave's 4 loads/q sit in one contiguous 4 KB region
// (64/256 B strides -> all sets used); both halves re-read the same 16 KB/q
// -> second half hits L1. Pack kernels run once (~8 MB traffic).
// Hard constraints (measured): acc <= 8 float4 (R6/R9); grid <= co-resident
// (R8); no agent-scope in-kernel barriers (R5); plain cached loads (R10);
// LDS-form FC tail (R10/R11); one variable per round.

constexpr int Bsz = 128, Tn = 256, In = 256, Hn = 1024, Cn = 10;
constexpr float LR = 0.001f;

__global__ __launch_bounds__(256) void k_transpose(const float* __restrict__ W,
                                                   float* __restrict__ WT) {
  __shared__ float tile[32][33];
  const int bx = blockIdx.x * 32, by = blockIdx.y * 32;
  const int tx = threadIdx.x & 31, ty = threadIdx.x >> 5;
#pragma unroll
  for (int dy = 0; dy < 32; dy += 8)
    tile[ty + dy][tx] = W[(size_t)(by + ty + dy) * Hn + bx + tx];
  __syncthreads();
#pragma unroll
  for (int dy = 0; dy < 32; dy += 8)
    WT[(size_t)(bx + ty + dy) * Hn + by + tx] = tile[tx][ty + dy];
}

// Pack W[k][c] -> Wp[ct][k][16] with ct = c>>4 (col-tile-major; 16 KB/tile).
__global__ __launch_bounds__(256) void k_pack(const float* __restrict__ W,
                                              float* __restrict__ Wp) {
  const int f = blockIdx.x * 256 + threadIdx.x;  // grid 1024 -> 256K float4
  const int k = f >> 8;
  const int c = (f & 255) * 4;
  const int ct = c >> 4, j = c & 15;
  *(float4*)&Wp[(size_t)ct * 16384 + (size_t)k * 16 + j] =
      *(const float4*)&W[(size_t)k * Hn + c];
}

__global__ __launch_bounds__(256) void k_init(float* __restrict__ out,
                                              const float* __restrict__ fc_b,
                                              float* __restrict__ h_cur,
                                              const float* __restrict__ hidden) {
  const int i = blockIdx.x * blockDim.x + threadIdx.x;
  if (i < Bsz * Tn * Cn) out[i] = fc_b[i % Cn];
  if (i < Bsz * Hn) h_cur[i] = hidden[i];
}

__device__ __forceinline__ void fma4(float4& a, float s, const float4& w) {
  a.x = fmaf(s, w.x, a.x);
  a.y = fmaf(s, w.y, a.y);
  a.z = fmaf(s, w.z, a.z);
  a.w = fmaf(s, w.w, a.w);
}

__device__ __forceinline__ float4 shfl4(float4 v, int m) {
  v.x = __shfl_xor(v.x, m, 64);
  v.y = __shfl_xor(v.y, m, 64);
  v.z = __shfl_xor(v.z, m, 64);
  v.w = __shfl_xor(v.w, m, 64);
  return v;
}

__device__ __forceinline__ float4 add4(float4 a, float4 b) {
  return make_float4(a.x + b.x, a.y + b.y, a.z + b.z, a.w + b.w);
}

// XW[t][b][n] = sum_k X[b][t][k]*Wx[k][n] + bias[n].
__global__ __launch_bounds__(256) void k_xw(const float* __restrict__ X,
                                            const float* __restrict__ Wx,
                                            const float* __restrict__ bias,
                                            float* __restrict__ xw) {
  const int nt = blockIdx.x & 15, mt = blockIdx.x >> 4;
  const int t = mt >> 1, b0 = (mt & 1) * 64;
  const int cl = threadIdx.x & 15, rg = threadIdx.x >> 4;
  const int col = nt * 64 + cl * 4;
  const int row = b0 + rg * 4;
  float4 acc0 = {0, 0, 0, 0}, acc1 = {0, 0, 0, 0}, acc2 = {0, 0, 0, 0},
         acc3 = {0, 0, 0, 0};
  const size_t xstride = (size_t)Tn * In;
  const float* xp = X + ((size_t)row * Tn + t) * In;
  const float* wp = Wx + col;
#pragma unroll 2
  for (int k = 0; k < In; k += 4) {
    const float4 x0 = *(const float4*)(xp + k);
    const float4 x1 = *(const float4*)(xp + xstride + k);
    const float4 x2 = *(const float4*)(xp + 2 * xstride + k);
    const float4 x3 = *(const float4*)(xp + 3 * xstride + k);
    const float4 w0 = *(const float4*)(wp + (size_t)k * Hn);
    const float4 w1 = *(const float4*)(wp + (size_t)(k + 1) * Hn);
    const float4 w2 = *(const float4*)(wp + (size_t)(k + 2) * Hn);
    const float4 w3 = *(const float4*)(wp + (size_t)(k + 3) * Hn);
    fma4(acc0, x0.x, w0); fma4(acc0, x0.y, w1); fma4(acc0, x0.z, w2); fma4(acc0, x0.w, w3);
    fma4(acc1, x1.x, w0); fma4(acc1, x1.y, w1); fma4(acc1, x1.z, w2); fma4(acc1, x1.w, w3);
    fma4(acc2, x2.x, w0); fma4(acc2, x2.y, w1); fma4(acc2, x2.z, w2); fma4(acc2, x2.w, w3);
    fma4(acc3, x3.x, w0); fma4(acc3, x3.y, w1); fma4(acc3, x3.z, w2); fma4(acc3, x3.w, w3);
  }
  const float4 b4 = *(const float4*)(bias + col);
  float4 o[4] = {acc0, acc1, acc2, acc3};
#pragma unroll
  for (int i = 0; i < 4; i++) {
    float4 v = o[i];
    v.x += b4.x; v.y += b4.y; v.z += b4.z; v.w += b4.w;
    *(float4*)(xw + ((size_t)t * Bsz + row + i) * Hn + col) = v;
  }
}

// 8-rows x 16-cols x K=1024 panel GEMM; per-half thread = c4(4) x kk(64).
// Rows direct from global. W from the PACKED col-tile (wtile = float4 base
// of this ct's 16 KB region): per q the wave's 4 loads sit in one contiguous
// 4 KB span -> full L1 set spread; sibling half re-reads it -> L1 hits.
__device__ __forceinline__ void gemm8g(const float* __restrict__ rows,
                                       const float4* __restrict__ wtile,
                                       int kk, int c4, float4 acc[8]) {
#pragma unroll
  for (int q = 0; q < 4; q++) {
    const int k = 4 * kk + 256 * q;
    const float4* Wp = wtile + (size_t)k * 4 + c4;
    const float4 w0 = Wp[0];
    const float4 w1 = Wp[4];
    const float4 w2 = Wp[8];
    const float4 w3 = Wp[12];
#pragma unroll
    for (int r = 0; r < 8; r++) {
      const float4 h4 = *(const float4*)(rows + (size_t)r * Hn + k);
      fma4(acc[r], h4.x, w0);
      fma4(acc[r], h4.y, w1);
      fma4(acc[r], h4.z, w2);
      fma4(acc[r], h4.w, w3);
    }
  }
}

// Value-splitting reduce over ks lane bits 2..5 (validated R5/R7/R12).
__device__ __forceinline__ void reduce_vs(float4 acc[8], int c4, int ksw,
                                          int wv, float (*part)[8][16]) {
  const bool u1 = ksw & 1;
#pragma unroll
  for (int i = 0; i < 4; i++) {
    const float4 snd = u1 ? acc[i] : acc[i + 4];
    const float4 kp = u1 ? acc[i + 4] : acc[i];
    acc[i] = add4(kp, shfl4(snd, 4));
  }
  const bool u2 = ksw & 2;
#pragma unroll
  for (int i = 0; i < 2; i++) {
    const float4 snd = u2 ? acc[i] : acc[i + 2];
    const float4 kp = u2 ? acc[i + 2] : acc[i];
    acc[i] = add4(kp, shfl4(snd, 8));
  }
  const bool u3 = ksw & 4;
  {
    const float4 snd = u3 ? acc[0] : acc[1];
    const float4 kp = u3 ? acc[1] : acc[0];
    acc[0] = add4(kp, shfl4(snd, 16));
  }
  const bool u4 = ksw & 8;
  float sx = u4 ? acc[0].x : acc[0].z;
  float sy = u4 ? acc[0].y : acc[0].w;
  const float kx = u4 ? acc[0].z : acc[0].x;
  const float ky = u4 ? acc[0].w : acc[0].y;
  sx = __shfl_xor(sx, 32, 64);
  sy = __shfl_xor(sy, 32, 64);
  const int r_own = ((ksw & 1) << 2) | (ksw & 2) | ((ksw >> 2) & 1);
  const int c_own = 4 * c4 + (u4 ? 2 : 0);
  *(float2*)&part[wv][r_own][c_own] = make_float2(kx + sx, ky + sy);
}

// grid 512 = rt(8, 16 rows) x ct(64, 16 cols); block 512 = half g(2) x 256.
// Half g owns rows r0+8g..r0+8g+7 (R14 geometry, R12 per-half core).
template <int PRE>
__global__ __launch_bounds__(512, 4) void k_phase1(
    const float* __restrict__ h, const float* __restrict__ X,
    const float* __restrict__ Whp, const float* __restrict__ Wx,
    const float* __restrict__ bias, const float* __restrict__ alpha,
    const float* __restrict__ xw, float* __restrict__ v_out, int t) {
  __shared__ float part[2][4][8][16];
  const int ct = blockIdx.x & 63, rt = blockIdx.x >> 6;
  const int c0 = ct * 16, r0 = rt * 16;
  const int tid = threadIdx.x;
  const int g = tid >> 8;
  const int c4 = tid & 3, kk = (tid >> 2) & 63;
  const int wvh = (tid >> 6) & 3, ksw = (tid & 63) >> 2;
  const float* hbase = h + (size_t)r0 * Hn;
  const float* hhalf = hbase + (size_t)(8 * g) * Hn;
  const float4* wtile = (const float4*)Whp + (size_t)ct * 4096;
  const float av = alpha[0];

  // epilogue prefetch (R12-proven)
  float a1 = 0.f, hv = 0.f;
  if (tid < 256) {
    const int r = tid >> 4, c = tid & 15;
    a1 = PRE ? xw[((size_t)t * Bsz + r0 + r) * Hn + c0 + c] : bias[c0 + c];
    hv = hbase[(size_t)r * Hn + c0 + c];
  }

  float4 acc[8];
#pragma unroll
  for (int r = 0; r < 8; r++) acc[r] = {0.f, 0.f, 0.f, 0.f};
  gemm8g(hhalf, wtile, kk, c4, acc);
  if (!PRE) {  // x@Wx inline per half (fallback path; Wx unpacked)
    const int kx = 4 * kk;
    const float* Wp = Wx + (size_t)kx * Hn + c0 + 4 * c4;
    const float4 w0 = *(const float4*)(Wp);
    const float4 w1 = *(const float4*)(Wp + Hn);
    const float4 w2 = *(const float4*)(Wp + 2 * Hn);
    const float4 w3 = *(const float4*)(Wp + 3 * Hn);
#pragma unroll
    for (int r = 0; r < 8; r++) {
      const float4 x4 = *(const float4*)(
          X + ((size_t)(r0 + 8 * g + r) * Tn + t) * In + kx);
      fma4(acc[r], x4.x, w0);
      fma4(acc[r], x4.y, w1);
      fma4(acc[r], x4.z, w2);
      fma4(acc[r], x4.w, w3);
    }
  }
  reduce_vs(acc, c4, ksw, wvh, part[g]);
  __syncthreads();
  if (tid < 256) {
    const int r = tid >> 4, c = tid & 15;
    const int g2 = r >> 3, rl = r & 7;
    const float u = part[g2][0][rl][c] + part[g2][1][rl][c] +
                    part[g2][2][rl][c] + part[g2][3][rl][c];
    v_out[(size_t)(r0 + r) * Hn + c0 + c] = av * hv - fmaxf(u + a1, 0.f);
  }
}

__global__ __launch_bounds__(512, 4) void k_phase2(
    float* __restrict__ h, const float* __restrict__ v_in,
    const float* __restrict__ WTp, const float* __restrict__ alpha,
    const float* __restrict__ fc_w, float* __restrict__ out,
    float* __restrict__ hfin, int t, int last) {
  __shared__ float part[2][4][8][16];
  __shared__ float hn_s[16][16];
  const int ct = blockIdx.x & 63, rt = blockIdx.x >> 6;
  const int c0 = ct * 16, r0 = rt * 16;
  const int tid = threadIdx.x;
  const int g = tid >> 8;
  const int c4 = tid & 3, kk = (tid >> 2) & 63;
  const int wvh = (tid >> 6) & 3, ksw = (tid & 63) >> 2;
  const float* vbase = v_in + (size_t)r0 * Hn;
  const float* vhalf = vbase + (size_t)(8 * g) * Hn;
  const float4* wtile = (const float4*)WTp + (size_t)ct * 4096;
  const float av = alpha[0];

  float hv = 0.f, vv = 0.f;
  if (tid < 256) {
    const int r = tid >> 4, c = tid & 15;
    hv = h[(size_t)(r0 + r) * Hn + c0 + c];
    vv = vbase[(size_t)r * Hn + c0 + c];
  }

  float4 acc[8];
#pragma unroll
  for (int r = 0; r < 8; r++) acc[r] = {0.f, 0.f, 0.f, 0.f};
  gemm8g(vhalf, wtile, kk, c4, acc);
  reduce_vs(acc, c4, ksw, wvh, part[g]);
  __syncthreads();
  if (tid < 256) {
    const int r = tid >> 4, c = tid & 15;
    const int g2 = r >> 3, rl = r & 7;
    const float u = part[g2][0][rl][c] + part[g2][1][rl][c] +
                    part[g2][2][rl][c] + part[g2][3][rl][c];
    const size_t hoff = (size_t)(r0 + r) * Hn + c0 + c;
    // phi = a*h - v; grad = a*v - (phi>0)*u; hn = h - LR*grad
    const float hn = hv - LR * (av * vv - ((av * hv - vv) > 0.f ? u : 0.f));
    h[hoff] = hn;
    if (last) hfin[hoff] = hn;
    hn_s[r][c] = hn;
  }
  __syncthreads();
  if (tid < 160) {  // FC partial over this block's 16 cols, 16 rows (R7 form)
    const int rr = tid / 10, c = tid % 10;
    float s = 0.f;
#pragma unroll
    for (int jj = 0; jj < 16; jj++)
      s += hn_s[rr][jj] * fc_w[(size_t)(c0 + jj) * Cn + c];
    atomicAdd(&out[((size_t)(r0 + rr) * Tn + t) * Cn + c], s);
  }
}

extern "C" void kernel_launch(void* const* d_in, const int* in_sizes, int n_in,
                              void* d_out, int out_size, void* d_ws, size_t ws_size,
                              hipStream_t stream) {
  const float* X      = (const float*)d_in[0];
  const float* hidden = (const float*)d_in[1];
  const float* alpha  = (const float*)d_in[2];
  const float* bias   = (const float*)d_in[3];
  const float* Wh     = (const float*)d_in[4];
  const float* Wx     = (const float*)d_in[5];
  const float* fc_w   = (const float*)d_in[6];
  const float* fc_b   = (const float*)d_in[7];
  float* out  = (float*)d_out;
  float* hfin = out + (size_t)Bsz * Tn * Cn;

  char* ws = (char*)d_ws;
  float* WhT   = (float*)ws;                        // 4 MB (scratch for pack)
  float* Whp   = WhT + (size_t)Hn * Hn;             // 4 MB packed Wh
  float* WTp   = Whp + (size_t)Hn * Hn;             // 4 MB packed Wh^T
  float* h_cur = WTp + (size_t)Hn * Hn;
  float* v_buf = h_cur + (size_t)Bsz * Hn;
  float* XW    = v_buf + (size_t)Bsz * Hn;          // 134 MB, [t][b][n]
  const size_t need =
      (3 * (size_t)Hn * Hn + 2 * (size_t)Bsz * Hn +
       (size_t)Bsz * Tn * Hn) * sizeof(float);
  const bool pre = ws_size >= need;

  k_transpose<<<dim3(32, 32), 256, 0, stream>>>(Wh, WhT);
  k_pack<<<1024, 256, 0, stream>>>(Wh, Whp);
  k_pack<<<1024, 256, 0, stream>>>(WhT, WTp);
  k_init<<<(Bsz * Tn * Cn + 255) / 256, 256, 0, stream>>>(out, fc_b, h_cur,
                                                          hidden);
  if (pre) k_xw<<<8192, 256, 0, stream>>>(X, Wx, bias, XW);
  for (int t = 0; t < Tn; t++) {
    if (pre)
      k_phase1<1><<<512, 512, 0, stream>>>(h_cur, X, Whp, Wx, bias, alpha, XW,
                                           v_buf, t);
    else
      k_phase1<0><<<512, 512, 0, stream>>>(h_cur, X, Whp, Wx, bias, alpha, XW,
                                           v_buf, t);
    k_phase2<<<512, 512, 0, stream>>>(h_cur, v_buf, WTp, alpha, fc_w, out,
                                      hfin, t, t == Tn - 1);
  }
}